// Round 7
// baseline (164.115 us; speedup 1.0000x reference)
//
#include <hip/hip_runtime.h>

typedef __bf16   bf16x8 __attribute__((ext_vector_type(8)));
typedef float    f32x4  __attribute__((ext_vector_type(4)));
typedef float    f32x2  __attribute__((ext_vector_type(2)));
typedef uint32_t u32x4  __attribute__((ext_vector_type(4)));

constexpr int N_ = 16384;
constexpr int D_ = 16;
constexpr int P_ = 8;
constexpr int H_ = 128;
constexpr int M_ = 50;

// prologue-only pack (round-half-up; matches the weight quantization of all
// passing rounds)
__device__ __forceinline__ uint32_t pk_bf16(float a, float b) {
    uint32_t ua = __builtin_bit_cast(uint32_t, a) + 0x8000u;
    uint32_t ub = __builtin_bit_cast(uint32_t, b) + 0x8000u;
    return __builtin_amdgcn_perm(ub, ua, 0x07060302u);   // low=a, high=b
}
// in-loop pack: single-instruction packed convert (RNE; validated R7/R8)
__device__ __forceinline__ uint32_t cvtpk(float a, float b) {
    uint32_t r;
    asm("v_cvt_pk_bf16_f32 %0, %1, %2" : "=v"(r) : "v"(a), "v"(b));
    return r;
}
__device__ __forceinline__ uint32_t cvtpk_relu(float a, float b) {
    return cvtpk(fmaxf(a, 0.0f), fmaxf(b, 0.0f));
}

// R10: 1 wave/SIMD (R0 base — 2-wave direction closed: R6/R7/R9 all spilled
// and ran slower) + DEPENDENT-CHAIN BREAKING, the lever R8's null isolated:
//  - R8 removed ~70 VALU/step -> VALUBusy 53->46 but dur flat: VALU is not
//    the critical path.
//  - Theory: layer 2 in source order = 8 sequential chains of 4 DEPENDENT
//    MFMAs; each link pays full result latency (~35 cyc) -> ~1100+ cyc/step
//    of pure latency. MfmaUtil 24% (pipe busy 645/2690 cyc) = latency-
//    serialized, not throughput-limited.
//  Fix, all source-order (no new regs, no LDS):
//   (1) layer-2 loop interchange: kt OUTER, ct inner -> 8 independent MFMAs
//       between each dependent pair (152-cyc cover >> latency);
//   (2) h1b[kt] packed inside the kt loop -> pack VALU lands between MFMA
//       groups, L2 starts after h1c[0..1] retire, not all 8;
//   (3) layer 3 = 4 independent MFMAs, summed in VALU (no 2-chains).
__global__ __launch_bounds__(64, 1)
void sde_fused(const float* __restrict__ X0,
               const float* __restrict__ V0,
               const float* __restrict__ Yobs,
               const float* __restrict__ noise,
               const float* __restrict__ W1, const float* __restrict__ b1,
               const float* __restrict__ W2, const float* __restrict__ b2,
               const float* __restrict__ W3, const float* __restrict__ b3,
               float* __restrict__ out)
{
    const int lane = threadIdx.x;
    const int n    = lane & 15;
    const int q    = lane >> 4;
    const int gr   = blockIdx.x * 16 + n;

    const float dt   = 0.02f;
    const float sqdt = 0.1414213562373095f;

    // ---- weight fragments, A-operand layout A[m=lane&15][k=q*8+j] ----
    bf16x8 w1f[8];
#pragma unroll
    for (int ct = 0; ct < 8; ++ct) {
        u32x4 u;
        u[0] = pk_bf16(W1[(1 + q * 4 + 0) * H_ + ct * 16 + n],
                       W1[(1 + q * 4 + 1) * H_ + ct * 16 + n]);
        u[1] = pk_bf16(W1[(1 + q * 4 + 2) * H_ + ct * 16 + n],
                       W1[(1 + q * 4 + 3) * H_ + ct * 16 + n]);
        u[2] = pk_bf16(W1[(17 + q * 2 + 0) * H_ + ct * 16 + n],
                       W1[(17 + q * 2 + 1) * H_ + ct * 16 + n]);
        u[3] = (q == 0) ? pk_bf16(b1[ct * 16 + n], W1[ct * 16 + n]) : 0u;
        w1f[ct] = __builtin_bit_cast(bf16x8, u);
    }
    bf16x8 w2f[8][4];
#pragma unroll
    for (int ct = 0; ct < 8; ++ct)
#pragma unroll
        for (int kt = 0; kt < 4; ++kt) {
            u32x4 u;
#pragma unroll
            for (int w = 0; w < 4; ++w) {
                int h0 = (kt * 2 + (w >> 1)) * 16 + q * 4 + (w & 1) * 2;
                u[w] = pk_bf16(W2[h0 * H_ + ct * 16 + n],
                               W2[(h0 + 1) * H_ + ct * 16 + n]);
            }
            w2f[ct][kt] = __builtin_bit_cast(bf16x8, u);
        }
    bf16x8 w3f[4];
#pragma unroll
    for (int kt = 0; kt < 4; ++kt) {
        u32x4 u;
#pragma unroll
        for (int w = 0; w < 4; ++w) {
            int h0 = (kt * 2 + (w >> 1)) * 16 + q * 4 + (w & 1) * 2;
            u[w] = pk_bf16(W3[h0 * D_ + n], W3[(h0 + 1) * D_ + n]);
        }
        w3f[kt] = __builtin_bit_cast(bf16x8, u);
    }
    f32x4 b2r[8];
#pragma unroll
    for (int ct = 0; ct < 8; ++ct)
#pragma unroll
        for (int r = 0; r < 4; ++r) b2r[ct][r] = b2[ct * 16 + q * 4 + r];
    f32x4 b3r;
#pragma unroll
    for (int r = 0; r < 4; ++r) b3r[r] = b3[q * 4 + r];

    // ---- state ----
    f32x4 x = *(const f32x4*)&X0[gr * D_ + q * 4];
    f32x2 y2 = *(const f32x2*)&Yobs[gr * P_ + q * 2];
    const uint32_t yw = pk_bf16(y2[0], y2[1]);   // constant word2 of a0

    const float* npb = noise + (size_t)gr * D_ + q * 4;
    f32x4 e0 = *(const f32x4*)npb;
    f32x4 e1 = *(const f32x4*)(npb + (size_t)N_ * D_);
    float t = 0.0f;
    float vacc = 0.0f;   // per-lane V partial, reduced once after the loop

#pragma unroll 1
    for (int m = 0; m < M_; ++m) {
        const int mp = (m + 2 < M_) ? (m + 2) : (M_ - 1);
        f32x4 e2 = *(const f32x4*)(npb + (size_t)mp * N_ * D_);

        // ---- layer 1 B fragment: [X(4) | Y(2) | one | t] ----
        u32x4 au;
        au[0] = cvtpk(x[0], x[1]);
        au[1] = cvtpk(x[2], x[3]);
        au[2] = yw;
        au[3] = (q == 0) ? cvtpk(1.0f, t) : 0u;
        bf16x8 a0 = __builtin_bit_cast(bf16x8, au);

        // ---- layer 1: 8 independent MFMAs ----
        f32x4 h1c[8];
#pragma unroll
        for (int ct = 0; ct < 8; ++ct)
            h1c[ct] = __builtin_amdgcn_mfma_f32_16x16x32_bf16(
                w1f[ct], a0, (f32x4){0.f, 0.f, 0.f, 0.f}, 0, 0, 0);

        // ---- layer 2, kt OUTER: every dependent link separated by 8
        //      independent MFMAs; packs interleave between MFMA groups ----
        f32x4 acc[8];
#pragma unroll
        for (int ct = 0; ct < 8; ++ct) acc[ct] = b2r[ct];
#pragma unroll
        for (int kt = 0; kt < 4; ++kt) {
            u32x4 u;
            u[0] = cvtpk_relu(h1c[2 * kt][0], h1c[2 * kt][1]);
            u[1] = cvtpk_relu(h1c[2 * kt][2], h1c[2 * kt][3]);
            u[2] = cvtpk_relu(h1c[2 * kt + 1][0], h1c[2 * kt + 1][1]);
            u[3] = cvtpk_relu(h1c[2 * kt + 1][2], h1c[2 * kt + 1][3]);
            bf16x8 hb = __builtin_bit_cast(bf16x8, u);
#pragma unroll
            for (int ct = 0; ct < 8; ++ct)
                acc[ct] = __builtin_amdgcn_mfma_f32_16x16x32_bf16(
                    w2f[ct][kt], hb, acc[ct], 0, 0, 0);
        }

        // ---- layer 3: 4 INDEPENDENT MFMAs (pack each B operand just
        //      before use; sum the 4 accumulators in VALU) ----
        u32x4 u0, u1, u2, u3;
        u0[0] = cvtpk_relu(acc[0][0], acc[0][1]);
        u0[1] = cvtpk_relu(acc[0][2], acc[0][3]);
        u0[2] = cvtpk_relu(acc[1][0], acc[1][1]);
        u0[3] = cvtpk_relu(acc[1][2], acc[1][3]);
        f32x4 z0 = __builtin_amdgcn_mfma_f32_16x16x32_bf16(
            w3f[0], __builtin_bit_cast(bf16x8, u0), b3r, 0, 0, 0);
        u1[0] = cvtpk_relu(acc[2][0], acc[2][1]);
        u1[1] = cvtpk_relu(acc[2][2], acc[2][3]);
        u1[2] = cvtpk_relu(acc[3][0], acc[3][1]);
        u1[3] = cvtpk_relu(acc[3][2], acc[3][3]);
        f32x4 z1 = __builtin_amdgcn_mfma_f32_16x16x32_bf16(
            w3f[1], __builtin_bit_cast(bf16x8, u1), (f32x4){0.f, 0.f, 0.f, 0.f}, 0, 0, 0);
        u2[0] = cvtpk_relu(acc[4][0], acc[4][1]);
        u2[1] = cvtpk_relu(acc[4][2], acc[4][3]);
        u2[2] = cvtpk_relu(acc[5][0], acc[5][1]);
        u2[3] = cvtpk_relu(acc[5][2], acc[5][3]);
        f32x4 z2 = __builtin_amdgcn_mfma_f32_16x16x32_bf16(
            w3f[2], __builtin_bit_cast(bf16x8, u2), (f32x4){0.f, 0.f, 0.f, 0.f}, 0, 0, 0);
        u3[0] = cvtpk_relu(acc[6][0], acc[6][1]);
        u3[1] = cvtpk_relu(acc[6][2], acc[6][3]);
        u3[2] = cvtpk_relu(acc[7][0], acc[7][1]);
        u3[3] = cvtpk_relu(acc[7][2], acc[7][3]);
        f32x4 z3 = __builtin_amdgcn_mfma_f32_16x16x32_bf16(
            w3f[3], __builtin_bit_cast(bf16x8, u3), (f32x4){0.f, 0.f, 0.f, 0.f}, 0, 0, 0);

        // ---- V partial + X update ----
#pragma unroll
        for (int r = 0; r < 4; ++r) {
            float z  = (z0[r] + z1[r]) + (z2[r] + z3[r]);
            float wn = sqdt * e0[r];
            vacc = fmaf(z, wn, fmaf(0.01f * z, z, vacc));   // z*wn + dt/2*z^2
            x[r] = fmaf(x[r], 0.98f, wn);                   // (1-dt)*x + wn
        }

        e0 = e1; e1 = e2;
        t += dt;
    }

    // ---- final V reduction across the 4 q-groups ----
    float part = vacc;
    part += __shfl_xor(part, 16);
    part += __shfl_xor(part, 32);
    float v = V0[gr] + part;

    *(f32x4*)&out[gr * D_ + q * 4] = x;
    if (q == 0) out[N_ * D_ + gr] = v;
}

extern "C" void kernel_launch(void* const* d_in, const int* in_sizes, int n_in,
                              void* d_out, int out_size, void* d_ws, size_t ws_size,
                              hipStream_t stream)
{
    const float* X0 = (const float*)d_in[0];
    const float* V0 = (const float*)d_in[1];
    const float* Y  = (const float*)d_in[2];
    const float* nz = (const float*)d_in[3];
    const float* W1 = (const float*)d_in[4];
    const float* b1 = (const float*)d_in[5];
    const float* W2 = (const float*)d_in[6];
    const float* b2 = (const float*)d_in[7];
    const float* W3 = (const float*)d_in[8];
    const float* b3 = (const float*)d_in[9];
    float* out = (float*)d_out;

    sde_fused<<<N_ / 16, 64, 0, stream>>>(X0, V0, Y, nz, W1, b1, W2, b2, W3, b3, out);
}

// Round 8
// 156.602 us; speedup vs baseline: 1.0480x; 1.0480x over previous
//
#include <hip/hip_runtime.h>

typedef __bf16   bf16x8 __attribute__((ext_vector_type(8)));
typedef float    f32x4  __attribute__((ext_vector_type(4)));
typedef float    f32x2  __attribute__((ext_vector_type(2)));
typedef uint32_t u32x4  __attribute__((ext_vector_type(4)));

constexpr int N_ = 16384;
constexpr int D_ = 16;
constexpr int P_ = 8;
constexpr int H_ = 128;
constexpr int M_ = 50;

// prologue-only pack (round-half-up; matches the weight quantization of all
// passing rounds)
__device__ __forceinline__ uint32_t pk_bf16(float a, float b) {
    uint32_t ua = __builtin_bit_cast(uint32_t, a) + 0x8000u;
    uint32_t ub = __builtin_bit_cast(uint32_t, b) + 0x8000u;
    return __builtin_amdgcn_perm(ub, ua, 0x07060302u);   // low=a, high=b
}
// in-loop pack: single-instruction packed convert (RNE; validated R7/R8)
__device__ __forceinline__ uint32_t cvtpk(float a, float b) {
    uint32_t r;
    asm("v_cvt_pk_bf16_f32 %0, %1, %2" : "=v"(r) : "v"(a), "v"(b));
    return r;
}
__device__ __forceinline__ uint32_t cvtpk_relu(float a, float b) {
    return cvtpk(fmaxf(a, 0.0f), fmaxf(b, 0.0f));
}

// R11: TWO-STEP-PER-ITERATION independent streams (discriminator experiment).
// R10 post-mortem: manual MFMA reordering added +1500 cyc/step of pure stall
// with identical pipe-busy time -> never hand-order against the scheduler;
// dependent-through-C chains are cheap (C-operand forwarding). Surviving
// theories: H1 = single-wave ILP starvation at layer joins; H2 = single-wave
// MFMA issue floor (~60 cyc/op regardless of independence).
// This kernel: steps m, m+1 are FULLY independent given x's 2-op recurrence
// (proven by R6 passing), so one wave carries 88 MFMAs of independent work
// per iteration. Streams A/B are separate named variables, each in R0/R8's
// proven per-step form, plain source order -- the SCHEDULER interleaves.
// Numerics: identical op order within each step; t computed as m*dt.
// H1 true -> 32-42 us. Flat -> H2 confirmed, next round changes occupancy
// (fp8-resident 2-wave) or MFMA count.
__global__ __launch_bounds__(64, 1)
void sde_fused(const float* __restrict__ X0,
               const float* __restrict__ V0,
               const float* __restrict__ Yobs,
               const float* __restrict__ noise,
               const float* __restrict__ W1, const float* __restrict__ b1,
               const float* __restrict__ W2, const float* __restrict__ b2,
               const float* __restrict__ W3, const float* __restrict__ b3,
               float* __restrict__ out)
{
    const int lane = threadIdx.x;
    const int n    = lane & 15;
    const int q    = lane >> 4;
    const int gr   = blockIdx.x * 16 + n;

    const float dt   = 0.02f;
    const float sqdt = 0.1414213562373095f;

    // ---- weight fragments, A-operand layout A[m=lane&15][k=q*8+j] ----
    bf16x8 w1f[8];
#pragma unroll
    for (int ct = 0; ct < 8; ++ct) {
        u32x4 u;
        u[0] = pk_bf16(W1[(1 + q * 4 + 0) * H_ + ct * 16 + n],
                       W1[(1 + q * 4 + 1) * H_ + ct * 16 + n]);
        u[1] = pk_bf16(W1[(1 + q * 4 + 2) * H_ + ct * 16 + n],
                       W1[(1 + q * 4 + 3) * H_ + ct * 16 + n]);
        u[2] = pk_bf16(W1[(17 + q * 2 + 0) * H_ + ct * 16 + n],
                       W1[(17 + q * 2 + 1) * H_ + ct * 16 + n]);
        u[3] = (q == 0) ? pk_bf16(b1[ct * 16 + n], W1[ct * 16 + n]) : 0u;
        w1f[ct] = __builtin_bit_cast(bf16x8, u);
    }
    bf16x8 w2f[8][4];
#pragma unroll
    for (int ct = 0; ct < 8; ++ct)
#pragma unroll
        for (int kt = 0; kt < 4; ++kt) {
            u32x4 u;
#pragma unroll
            for (int w = 0; w < 4; ++w) {
                int h0 = (kt * 2 + (w >> 1)) * 16 + q * 4 + (w & 1) * 2;
                u[w] = pk_bf16(W2[h0 * H_ + ct * 16 + n],
                               W2[(h0 + 1) * H_ + ct * 16 + n]);
            }
            w2f[ct][kt] = __builtin_bit_cast(bf16x8, u);
        }
    bf16x8 w3f[4];
#pragma unroll
    for (int kt = 0; kt < 4; ++kt) {
        u32x4 u;
#pragma unroll
        for (int w = 0; w < 4; ++w) {
            int h0 = (kt * 2 + (w >> 1)) * 16 + q * 4 + (w & 1) * 2;
            u[w] = pk_bf16(W3[h0 * D_ + n], W3[(h0 + 1) * D_ + n]);
        }
        w3f[kt] = __builtin_bit_cast(bf16x8, u);
    }
    f32x4 b2r[8];
#pragma unroll
    for (int ct = 0; ct < 8; ++ct)
#pragma unroll
        for (int r = 0; r < 4; ++r) b2r[ct][r] = b2[ct * 16 + q * 4 + r];
    f32x4 b3r;
#pragma unroll
    for (int r = 0; r < 4; ++r) b3r[r] = b3[q * 4 + r];

    // ---- state ----
    f32x4 x = *(const f32x4*)&X0[gr * D_ + q * 4];
    f32x2 y2 = *(const f32x2*)&Yobs[gr * P_ + q * 2];
    const uint32_t yw = pk_bf16(y2[0], y2[1]);   // constant word2 of a0

    const float* npb = noise + (size_t)gr * D_ + q * 4;
    f32x4 e0 = *(const f32x4*)npb;                            // eps[mm]
    f32x4 e1 = *(const f32x4*)(npb + (size_t)N_ * D_);        // eps[mm+1]
    float vaccA = 0.0f, vaccB = 0.0f;

#pragma unroll 1
    for (int mm = 0; mm < M_; mm += 2) {
        const int p0 = (mm + 2 < M_) ? (mm + 2) : (M_ - 1);
        const int p1 = (mm + 3 < M_) ? (mm + 3) : (M_ - 1);
        f32x4 eN0 = *(const f32x4*)(npb + (size_t)p0 * N_ * D_);
        f32x4 eN1 = *(const f32x4*)(npb + (size_t)p1 * N_ * D_);

        const float tA = (float)mm * dt;
        const float tB = (float)(mm + 1) * dt;

        // stream B's X state (depends only on x, e0 — available immediately)
        f32x4 xB;
#pragma unroll
        for (int r = 0; r < 4; ++r) xB[r] = fmaf(x[r], 0.98f, sqdt * e0[r]);

        // ---- layer-1 B fragments for both steps ----
        u32x4 auA;
        auA[0] = cvtpk(x[0], x[1]);
        auA[1] = cvtpk(x[2], x[3]);
        auA[2] = yw;
        auA[3] = (q == 0) ? cvtpk(1.0f, tA) : 0u;
        bf16x8 a0A = __builtin_bit_cast(bf16x8, auA);
        u32x4 auB;
        auB[0] = cvtpk(xB[0], xB[1]);
        auB[1] = cvtpk(xB[2], xB[3]);
        auB[2] = yw;
        auB[3] = (q == 0) ? cvtpk(1.0f, tB) : 0u;
        bf16x8 a0B = __builtin_bit_cast(bf16x8, auB);

        // ---- layer 1: 16 independent MFMAs across the two streams ----
        f32x4 h1cA[8], h1cB[8];
#pragma unroll
        for (int ct = 0; ct < 8; ++ct)
            h1cA[ct] = __builtin_amdgcn_mfma_f32_16x16x32_bf16(
                w1f[ct], a0A, (f32x4){0.f, 0.f, 0.f, 0.f}, 0, 0, 0);
#pragma unroll
        for (int ct = 0; ct < 8; ++ct)
            h1cB[ct] = __builtin_amdgcn_mfma_f32_16x16x32_bf16(
                w1f[ct], a0B, (f32x4){0.f, 0.f, 0.f, 0.f}, 0, 0, 0);

        bf16x8 h1bA[4], h1bB[4];
#pragma unroll
        for (int kt = 0; kt < 4; ++kt) {
            u32x4 u;
            u[0] = cvtpk_relu(h1cA[2 * kt][0], h1cA[2 * kt][1]);
            u[1] = cvtpk_relu(h1cA[2 * kt][2], h1cA[2 * kt][3]);
            u[2] = cvtpk_relu(h1cA[2 * kt + 1][0], h1cA[2 * kt + 1][1]);
            u[3] = cvtpk_relu(h1cA[2 * kt + 1][2], h1cA[2 * kt + 1][3]);
            h1bA[kt] = __builtin_bit_cast(bf16x8, u);
        }
#pragma unroll
        for (int kt = 0; kt < 4; ++kt) {
            u32x4 u;
            u[0] = cvtpk_relu(h1cB[2 * kt][0], h1cB[2 * kt][1]);
            u[1] = cvtpk_relu(h1cB[2 * kt][2], h1cB[2 * kt][3]);
            u[2] = cvtpk_relu(h1cB[2 * kt + 1][0], h1cB[2 * kt + 1][1]);
            u[3] = cvtpk_relu(h1cB[2 * kt + 1][2], h1cB[2 * kt + 1][3]);
            h1bB[kt] = __builtin_bit_cast(bf16x8, u);
        }

        // ---- layer 2: 16 independent chains of 4 (R0's proven form) ----
        f32x4 h2cA[8], h2cB[8];
#pragma unroll
        for (int ct = 0; ct < 8; ++ct) {
            f32x4 c = b2r[ct];
#pragma unroll
            for (int kt = 0; kt < 4; ++kt)
                c = __builtin_amdgcn_mfma_f32_16x16x32_bf16(
                    w2f[ct][kt], h1bA[kt], c, 0, 0, 0);
            h2cA[ct] = c;
        }
#pragma unroll
        for (int ct = 0; ct < 8; ++ct) {
            f32x4 c = b2r[ct];
#pragma unroll
            for (int kt = 0; kt < 4; ++kt)
                c = __builtin_amdgcn_mfma_f32_16x16x32_bf16(
                    w2f[ct][kt], h1bB[kt], c, 0, 0, 0);
            h2cB[ct] = c;
        }

        bf16x8 h2bA[4], h2bB[4];
#pragma unroll
        for (int kt = 0; kt < 4; ++kt) {
            u32x4 u;
            u[0] = cvtpk_relu(h2cA[2 * kt][0], h2cA[2 * kt][1]);
            u[1] = cvtpk_relu(h2cA[2 * kt][2], h2cA[2 * kt][3]);
            u[2] = cvtpk_relu(h2cA[2 * kt + 1][0], h2cA[2 * kt + 1][1]);
            u[3] = cvtpk_relu(h2cA[2 * kt + 1][2], h2cA[2 * kt + 1][3]);
            h2bA[kt] = __builtin_bit_cast(bf16x8, u);
        }
#pragma unroll
        for (int kt = 0; kt < 4; ++kt) {
            u32x4 u;
            u[0] = cvtpk_relu(h2cB[2 * kt][0], h2cB[2 * kt][1]);
            u[1] = cvtpk_relu(h2cB[2 * kt][2], h2cB[2 * kt][3]);
            u[2] = cvtpk_relu(h2cB[2 * kt + 1][0], h2cB[2 * kt + 1][1]);
            u[3] = cvtpk_relu(h2cB[2 * kt + 1][2], h2cB[2 * kt + 1][3]);
            h2bB[kt] = __builtin_bit_cast(bf16x8, u);
        }

        // ---- layer 3: two 2-chains per stream (R0's form) ----
        f32x4 zaA = __builtin_amdgcn_mfma_f32_16x16x32_bf16(w3f[0], h2bA[0], b3r, 0, 0, 0);
        zaA = __builtin_amdgcn_mfma_f32_16x16x32_bf16(w3f[1], h2bA[1], zaA, 0, 0, 0);
        f32x4 zbA = __builtin_amdgcn_mfma_f32_16x16x32_bf16(
            w3f[2], h2bA[2], (f32x4){0.f, 0.f, 0.f, 0.f}, 0, 0, 0);
        zbA = __builtin_amdgcn_mfma_f32_16x16x32_bf16(w3f[3], h2bA[3], zbA, 0, 0, 0);
        f32x4 zaB = __builtin_amdgcn_mfma_f32_16x16x32_bf16(w3f[0], h2bB[0], b3r, 0, 0, 0);
        zaB = __builtin_amdgcn_mfma_f32_16x16x32_bf16(w3f[1], h2bB[1], zaB, 0, 0, 0);
        f32x4 zbB = __builtin_amdgcn_mfma_f32_16x16x32_bf16(
            w3f[2], h2bB[2], (f32x4){0.f, 0.f, 0.f, 0.f}, 0, 0, 0);
        zbB = __builtin_amdgcn_mfma_f32_16x16x32_bf16(w3f[3], h2bB[3], zbB, 0, 0, 0);

        // ---- V partials + advance X through both steps ----
#pragma unroll
        for (int r = 0; r < 4; ++r) {
            float zA  = zaA[r] + zbA[r];
            float wnA = sqdt * e0[r];
            vaccA = fmaf(zA, wnA, fmaf(0.01f * zA, zA, vaccA));
            float zB  = zaB[r] + zbB[r];
            float wnB = sqdt * e1[r];
            vaccB = fmaf(zB, wnB, fmaf(0.01f * zB, zB, vaccB));
            x[r] = fmaf(xB[r], 0.98f, wnB);                 // x after step mm+1
        }

        e0 = eN0; e1 = eN1;
    }

    // ---- final V reduction across the 4 q-groups ----
    float part = vaccA + vaccB;
    part += __shfl_xor(part, 16);
    part += __shfl_xor(part, 32);
    float v = V0[gr] + part;

    *(f32x4*)&out[gr * D_ + q * 4] = x;
    if (q == 0) out[N_ * D_ + gr] = v;
}

extern "C" void kernel_launch(void* const* d_in, const int* in_sizes, int n_in,
                              void* d_out, int out_size, void* d_ws, size_t ws_size,
                              hipStream_t stream)
{
    const float* X0 = (const float*)d_in[0];
    const float* V0 = (const float*)d_in[1];
    const float* Y  = (const float*)d_in[2];
    const float* nz = (const float*)d_in[3];
    const float* W1 = (const float*)d_in[4];
    const float* b1 = (const float*)d_in[5];
    const float* W2 = (const float*)d_in[6];
    const float* b2 = (const float*)d_in[7];
    const float* W3 = (const float*)d_in[8];
    const float* b3 = (const float*)d_in[9];
    float* out = (float*)d_out;

    sde_fused<<<N_ / 16, 64, 0, stream>>>(X0, V0, Y, nz, W1, b1, W2, b2, W3, b3, out);
}